// Round 2
// baseline (20487.602 us; speedup 1.0000x reference)
//
#include <hip/hip_runtime.h>

#define EMBD 300
#define GG   4096
#define NLAY 5

// ---------------- elementwise kernels ----------------

__global__ void atom_encode(const int* __restrict__ x, const float* __restrict__ aemb,
                            float* __restrict__ h, int N) {
    int i = blockIdx.x * blockDim.x + threadIdx.x;
    int total = N * EMBD;
    if (i >= total) return;
    int n = i / EMBD, d = i - n * EMBD;
    const int* xr = x + n * 9;
    float s = 0.f;
#pragma unroll
    for (int f = 0; f < 9; ++f) {
        int idx = xr[f];
        s += aemb[((f << 7) + idx) * EMBD + d];
    }
    h[i] = s;
}

__global__ void init_vn(const float* __restrict__ vn_emb, float* __restrict__ vn) {
    int i = blockIdx.x * blockDim.x + threadIdx.x;
    if (i >= GG * EMBD) return;
    vn[i] = vn_emb[i % EMBD];
}

__global__ void count_nodes(const int* __restrict__ batch, float* __restrict__ counts, int N) {
    int n = blockIdx.x * blockDim.x + threadIdx.x;
    if (n >= N) return;
    atomicAdd(&counts[batch[n]], 1.0f);
}

// h += vn[batch]; agg = (1+eps)*h_new; optional pooled += h_new
__global__ void prep_layer(float* __restrict__ h, float* __restrict__ agg,
                           const float* __restrict__ vn, const int* __restrict__ batch,
                           const float* __restrict__ epsp, float* __restrict__ pooled,
                           int N, int do_pool) {
    int i = blockIdx.x * blockDim.x + threadIdx.x;
    int total = N * EMBD;
    if (i >= total) return;
    int n = i / EMBD, d = i - n * EMBD;
    int g = batch[n];
    float nh = h[i] + vn[(size_t)g * EMBD + d];
    h[i] = nh;
    agg[i] = (1.0f + *epsp) * nh;
    if (do_pool) atomicAdd(&pooled[(size_t)g * EMBD + d], nh);
}

// agg[col] += relu(h[row] + bond_embed(edge))
__global__ void edge_scatter(const float* __restrict__ h, const int* __restrict__ ei,
                             const int* __restrict__ ea, const float* __restrict__ bemb,
                             float* __restrict__ agg, int E) {
    int i = blockIdx.x * blockDim.x + threadIdx.x;
    int total = E * EMBD;
    if (i >= total) return;
    int e = i / EMBD, d = i - e * EMBD;
    int r = ei[e];
    int c = ei[E + e];
    int a0 = ea[e * 3 + 0], a1 = ea[e * 3 + 1], a2 = ea[e * 3 + 2];
    float ev = bemb[(a0)*EMBD + d] + bemb[(8 + a1) * EMBD + d] + bemb[(16 + a2) * EMBD + d];
    float m = h[(size_t)r * EMBD + d] + ev;
    if (m > 0.f) atomicAdd(&agg[(size_t)c * EMBD + d], m);
}

__global__ void pool_h(const float* __restrict__ h, const int* __restrict__ batch,
                       float* __restrict__ pooled, int N) {
    int i = blockIdx.x * blockDim.x + threadIdx.x;
    int total = N * EMBD;
    if (i >= total) return;
    int n = i / EMBD, d = i - n * EMBD;
    atomicAdd(&pooled[(size_t)batch[n] * EMBD + d], h[i]);
}

__global__ void mean_div(float* __restrict__ out, const float* __restrict__ counts) {
    int i = blockIdx.x * blockDim.x + threadIdx.x;
    if (i >= GG * EMBD) return;
    int g = i / EMBD;
    out[i] /= fmaxf(counts[g], 1.0f);
}

// ---------------- generic fused GEMM + bias + BN (+relu) ----------------
// C[M,Nn] = epilogue( (A + A2) @ B )
// epilogue: y = (acc + bias[j] - bm[j]) * (g[j]*rsqrt(bv[j]+eps)) + bb[j]; relu optional
#define BM 128
#define BN 64
#define BK 16

__global__ __launch_bounds__(256) void gemm_bn(
    const float* __restrict__ A, const float* __restrict__ A2,
    const float* __restrict__ B, const float* __restrict__ bias,
    const float* __restrict__ g, const float* __restrict__ bb,
    const float* __restrict__ bm, const float* __restrict__ bv,
    float* __restrict__ C, int M, int Nn, int K, int relu)
{
    __shared__ float As[BK][BM + 4];
    __shared__ float Bs[BK][BN];

    int tid = threadIdx.x;
    int tx = tid & 15, ty = tid >> 4;
    int m0 = blockIdx.y * BM, n0 = blockIdx.x * BN;

    float acc[8][4];
#pragma unroll
    for (int i = 0; i < 8; ++i)
#pragma unroll
        for (int j = 0; j < 4; ++j) acc[i][j] = 0.f;

    for (int k0 = 0; k0 < K; k0 += BK) {
        // ---- load A tile (BM x BK), store transposed As[k][m]
#pragma unroll
        for (int it = 0; it < 2; ++it) {
            int q = tid + 256 * it;        // 0..511 float4 slots
            int am = q >> 2;               // 0..127
            int ak = (q & 3) << 2;         // 0,4,8,12
            int gm = m0 + am, gk = k0 + ak;
            float4 v = make_float4(0.f, 0.f, 0.f, 0.f);
            if (gm < M) {
                const float* Ap = A + (size_t)gm * K;
                if (gk + 4 <= K) {
                    v = *(const float4*)(Ap + gk);
                    if (A2) {
                        const float4 w = *(const float4*)(A2 + (size_t)gm * K + gk);
                        v.x += w.x; v.y += w.y; v.z += w.z; v.w += w.w;
                    }
                } else {
                    float t[4] = {0.f, 0.f, 0.f, 0.f};
#pragma unroll
                    for (int j = 0; j < 4; ++j) {
                        if (gk + j < K) {
                            float av = Ap[gk + j];
                            if (A2) av += A2[(size_t)gm * K + gk + j];
                            t[j] = av;
                        }
                    }
                    v = make_float4(t[0], t[1], t[2], t[3]);
                }
            }
            As[ak + 0][am] = v.x;
            As[ak + 1][am] = v.y;
            As[ak + 2][am] = v.z;
            As[ak + 3][am] = v.w;
        }
        // ---- load B tile (BK x BN)
        {
            int br = tid >> 4;             // 0..15
            int bc = (tid & 15) << 2;      // 0..60
            int gk = k0 + br, gn = n0 + bc;
            float4 v = make_float4(0.f, 0.f, 0.f, 0.f);
            if (gk < K) {
                const float* Bp = B + (size_t)gk * Nn;
                if (gn + 4 <= Nn) {
                    v = *(const float4*)(Bp + gn);
                } else {
                    float t[4] = {0.f, 0.f, 0.f, 0.f};
#pragma unroll
                    for (int j = 0; j < 4; ++j)
                        if (gn + j < Nn) t[j] = Bp[gn + j];
                    v = make_float4(t[0], t[1], t[2], t[3]);
                }
            }
            *(float4*)&Bs[br][bc] = v;
        }
        __syncthreads();

#pragma unroll
        for (int kk = 0; kk < BK; ++kk) {
            float4 a0 = *(const float4*)&As[kk][8 * ty];
            float4 a1 = *(const float4*)&As[kk][8 * ty + 4];
            float4 b4 = *(const float4*)&Bs[kk][4 * tx];
            float a[8] = {a0.x, a0.y, a0.z, a0.w, a1.x, a1.y, a1.z, a1.w};
            float b[4] = {b4.x, b4.y, b4.z, b4.w};
#pragma unroll
            for (int i = 0; i < 8; ++i)
#pragma unroll
                for (int j = 0; j < 4; ++j) acc[i][j] += a[i] * b[j];
        }
        __syncthreads();
    }

    // ---- epilogue
#pragma unroll
    for (int j = 0; j < 4; ++j) {
        int gn = n0 + 4 * tx + j;
        if (gn >= Nn) continue;
        float sc = g[gn] * rsqrtf(bv[gn] + 1e-5f);
        float sh = bb[gn] + (bias[gn] - bm[gn]) * sc;
#pragma unroll
        for (int i = 0; i < 8; ++i) {
            int gm = m0 + 8 * ty + i;
            if (gm < M) {
                float v = acc[i][j] * sc + sh;
                if (relu) v = fmaxf(v, 0.f);
                C[(size_t)gm * Nn + gn] = v;
            }
        }
    }
}

// ---------------- host ----------------

static inline int cdiv(int a, int b) { return (a + b - 1) / b; }

extern "C" void kernel_launch(void* const* d_in, const int* in_sizes, int n_in,
                              void* d_out, int out_size, void* d_ws, size_t ws_size,
                              hipStream_t stream) {
    const int*   x        = (const int*)d_in[0];
    const int*   ei       = (const int*)d_in[1];
    const int*   ea       = (const int*)d_in[2];
    const int*   batch    = (const int*)d_in[3];
    const float* atom_emb = (const float*)d_in[4];
    const float* bond_emb = (const float*)d_in[5];
    const float* vn_emb   = (const float*)d_in[6];
    const float* gin_eps  = (const float*)d_in[7];
    const float* gin_W1   = (const float*)d_in[8];
    const float* gin_b1   = (const float*)d_in[9];
    const float* gin_bn1g = (const float*)d_in[10];
    const float* gin_bn1b = (const float*)d_in[11];
    const float* gin_bn1m = (const float*)d_in[12];
    const float* gin_bn1v = (const float*)d_in[13];
    const float* gin_W2   = (const float*)d_in[14];
    const float* gin_b2   = (const float*)d_in[15];
    const float* bn_g     = (const float*)d_in[16];
    const float* bn_b     = (const float*)d_in[17];
    const float* bn_m     = (const float*)d_in[18];
    const float* bn_v     = (const float*)d_in[19];
    const float* vn_W1    = (const float*)d_in[20];
    const float* vn_b1    = (const float*)d_in[21];
    const float* vn_bn1g  = (const float*)d_in[22];
    const float* vn_bn1b  = (const float*)d_in[23];
    const float* vn_bn1m  = (const float*)d_in[24];
    const float* vn_bn1v  = (const float*)d_in[25];
    const float* vn_W2    = (const float*)d_in[26];
    const float* vn_b2    = (const float*)d_in[27];
    const float* vn_bn2g  = (const float*)d_in[28];
    const float* vn_bn2b  = (const float*)d_in[29];
    const float* vn_bn2m  = (const float*)d_in[30];
    const float* vn_bn2v  = (const float*)d_in[31];

    const int N = in_sizes[3];
    const int E = in_sizes[1] / 2;

    // ---- workspace layout (size-aware) ----
    float* ws = (float*)d_ws;
    size_t off = 0;
    float* hbuf   = ws + off; off += (size_t)N * EMBD;      // 120 MB
    float* agg    = ws + off; off += (size_t)N * EMBD;      // 120 MB
    float* pooled = ws + off; off += (size_t)GG * EMBD;
    float* ubuf   = ws + off; off += (size_t)GG * 2 * EMBD;
    float* vnbuf  = ws + off; off += (size_t)GG * EMBD;
    float* counts = ws + off; off += GG;
    float* t2     = ws + off;                               // adaptive chunk

    size_t ws_floats = ws_size / sizeof(float);
    size_t avail = (ws_floats > off) ? (ws_floats - off) : 0;
    int CH = (int)((avail / (2 * EMBD) < (size_t)N) ? (avail / (2 * EMBD)) : (size_t)N);
    if (CH < BM) CH = BM;  // last-resort clamp

    const int BLK = 256;
    int ne = N * EMBD;
    int ee = E * EMBD;
    int ge = GG * EMBD;

    // encoders / init
    atom_encode<<<cdiv(ne, BLK), BLK, 0, stream>>>(x, atom_emb, hbuf, N);
    init_vn<<<cdiv(ge, BLK), BLK, 0, stream>>>(vn_emb, vnbuf);
    hipMemsetAsync(counts, 0, GG * sizeof(float), stream);
    count_nodes<<<cdiv(N, BLK), BLK, 0, stream>>>(batch, counts, N);

    for (int l = 0; l < NLAY; ++l) {
        int do_pool = (l < NLAY - 1) ? 1 : 0;
        if (do_pool)
            hipMemsetAsync(pooled, 0, (size_t)GG * EMBD * sizeof(float), stream);

        // h += vn[batch]; agg = (1+eps)h; pooled += h
        prep_layer<<<cdiv(ne, BLK), BLK, 0, stream>>>(hbuf, agg, vnbuf, batch,
                                                      gin_eps + l, pooled, N, do_pool);

        // agg += scatter_add(relu(h[row] + e))
        edge_scatter<<<cdiv(ee, BLK), BLK, 0, stream>>>(hbuf, ei, ea, bond_emb, agg, E);

        // node MLP, chunked over rows; GEMM2 writes back into hbuf in place
        for (int c0 = 0; c0 < N; c0 += CH) {
            int Mc = (N - c0 < CH) ? (N - c0) : CH;
            {
                dim3 grid(cdiv(2 * EMBD, BN), cdiv(Mc, BM));
                gemm_bn<<<grid, 256, 0, stream>>>(
                    agg + (size_t)c0 * EMBD, nullptr,
                    gin_W1 + (size_t)l * EMBD * 2 * EMBD, gin_b1 + (size_t)l * 2 * EMBD,
                    gin_bn1g + (size_t)l * 2 * EMBD, gin_bn1b + (size_t)l * 2 * EMBD,
                    gin_bn1m + (size_t)l * 2 * EMBD, gin_bn1v + (size_t)l * 2 * EMBD,
                    t2, Mc, 2 * EMBD, EMBD, 1);
            }
            {
                dim3 grid(cdiv(EMBD, BN), cdiv(Mc, BM));
                gemm_bn<<<grid, 256, 0, stream>>>(
                    t2, nullptr,
                    gin_W2 + (size_t)l * 2 * EMBD * EMBD, gin_b2 + (size_t)l * EMBD,
                    bn_g + (size_t)l * EMBD, bn_b + (size_t)l * EMBD,
                    bn_m + (size_t)l * EMBD, bn_v + (size_t)l * EMBD,
                    hbuf + (size_t)c0 * EMBD, Mc, EMBD, 2 * EMBD, do_pool);
            }
        }

        if (do_pool) {
            // u = relu(bn1( (pooled+vn) @ vnW1 + vnb1 ))   [G, 600]
            {
                dim3 grid(cdiv(2 * EMBD, BN), cdiv(GG, BM));
                gemm_bn<<<grid, 256, 0, stream>>>(
                    pooled, vnbuf,
                    vn_W1 + (size_t)l * EMBD * 2 * EMBD, vn_b1 + (size_t)l * 2 * EMBD,
                    vn_bn1g + (size_t)l * 2 * EMBD, vn_bn1b + (size_t)l * 2 * EMBD,
                    vn_bn1m + (size_t)l * 2 * EMBD, vn_bn1v + (size_t)l * 2 * EMBD,
                    ubuf, GG, 2 * EMBD, EMBD, 1);
            }
            // vn = relu(bn2( u @ vnW2 + vnb2 ))            [G, 300]
            {
                dim3 grid(cdiv(EMBD, BN), cdiv(GG, BM));
                gemm_bn<<<grid, 256, 0, stream>>>(
                    ubuf, nullptr,
                    vn_W2 + (size_t)l * 2 * EMBD * EMBD, vn_b2 + (size_t)l * EMBD,
                    vn_bn2g + (size_t)l * EMBD, vn_bn2b + (size_t)l * EMBD,
                    vn_bn2m + (size_t)l * EMBD, vn_bn2v + (size_t)l * EMBD,
                    vnbuf, GG, EMBD, 2 * EMBD, 1);
            }
        }
    }

    // out = segment_sum(h, batch) / max(counts, 1)
    hipMemsetAsync(d_out, 0, (size_t)GG * EMBD * sizeof(float), stream);
    pool_h<<<cdiv(ne, BLK), BLK, 0, stream>>>(hbuf, batch, (float*)d_out, N);
    mean_div<<<cdiv(ge, BLK), BLK, 0, stream>>>((float*)d_out, counts);
}

// Round 3
// 14208.606 us; speedup vs baseline: 1.4419x; 1.4419x over previous
//
#include <hip/hip_runtime.h>
#include <hip/hip_bf16.h>

#define EMBD 300
#define GG   4096
#define NLAY 5
#define KP1  320   // padded K for EMB=300 inputs
#define KP2  640   // padded K for 2*EMB=600 inputs
#define NP1  640   // padded Nn for 600-col outputs
#define NP2  320   // padded Nn for 300-col outputs

typedef unsigned short ushort_t;
typedef short short8 __attribute__((ext_vector_type(8)));
typedef float f32x4 __attribute__((ext_vector_type(4)));

static inline int cdiv(int a, int b) { return (a + b - 1) / b; }

// ---------------- helpers ----------------

__device__ inline void dma16(const ushort_t* g, ushort_t* l) {
    // global -> LDS direct copy, 16B per lane; LDS dest = wave-uniform base + lane*16
    __builtin_amdgcn_global_load_lds(
        (const __attribute__((address_space(1))) unsigned int*)g,
        (__attribute__((address_space(3))) unsigned int*)l, 16, 0, 0);
}

__device__ inline ushort_t bf16_hi(float v) {
    union { __hip_bfloat16 b; ushort_t u; } c;
    c.b = __float2bfloat16(v);
    return c.u;
}
__device__ inline void bf16_split(float v, ushort_t& h, ushort_t& l) {
    union { __hip_bfloat16 b; ushort_t u; } c;
    c.b = __float2bfloat16(v);
    h = c.u;
    float hf = __bfloat162float(c.b);
    c.b = __float2bfloat16(v - hf);
    l = c.u;
}

// ---------------- elementwise kernels (float4) ----------------

__global__ void atom_encode4(const int* __restrict__ x, const float* __restrict__ aemb,
                             float* __restrict__ h, int N) {
    int i = blockIdx.x * blockDim.x + threadIdx.x;
    int total = N * 75;
    if (i >= total) return;
    int n = i / 75, d4 = i - n * 75;
    const int* xr = x + n * 9;
    float4 s = make_float4(0.f, 0.f, 0.f, 0.f);
    const float4* a4 = (const float4*)aemb;
#pragma unroll
    for (int f = 0; f < 9; ++f) {
        float4 v = a4[(size_t)((f << 7) + xr[f]) * 75 + d4];
        s.x += v.x; s.y += v.y; s.z += v.z; s.w += v.w;
    }
    ((float4*)h)[i] = s;
}

__global__ void init_vn4(const float* __restrict__ vn_emb, float* __restrict__ vn) {
    int i = blockIdx.x * blockDim.x + threadIdx.x;
    if (i >= GG * 75) return;
    ((float4*)vn)[i] = ((const float4*)vn_emb)[i % 75];
}

__global__ void find_starts(const int* __restrict__ batch, int* __restrict__ starts, int N) {
    int g = blockIdx.x * blockDim.x + threadIdx.x;
    if (g > GG) return;
    int lo = 0, hi = N;
    while (lo < hi) {
        int mid = (lo + hi) >> 1;
        if (batch[mid] < g) lo = mid + 1; else hi = mid;
    }
    starts[g] = lo;
}

// h += vn[batch]; agg = (1+eps)*h_new
__global__ void prep4(float* __restrict__ h, float* __restrict__ agg,
                      const float* __restrict__ vn, const int* __restrict__ batch,
                      const float* __restrict__ epsp, int N) {
    int i = blockIdx.x * blockDim.x + threadIdx.x;
    int total = N * 75;
    if (i >= total) return;
    int n = i / 75, d4 = i - n * 75;
    int g = batch[n];
    float ce = 1.0f + *epsp;
    float4 hv = ((const float4*)h)[i];
    float4 vv = ((const float4*)vn)[(size_t)g * 75 + d4];
    hv.x += vv.x; hv.y += vv.y; hv.z += vv.z; hv.w += vv.w;
    ((float4*)h)[i] = hv;
    float4 av = make_float4(ce * hv.x, ce * hv.y, ce * hv.z, ce * hv.w);
    ((float4*)agg)[i] = av;
}

// agg[col] += relu(h[row] + bond_embed(edge))
__global__ void edge_scatter4(const float* __restrict__ h, const int* __restrict__ ei,
                              const int* __restrict__ ea, const float* __restrict__ bemb,
                              float* __restrict__ agg, int E) {
    int i = blockIdx.x * blockDim.x + threadIdx.x;
    int total = E * 75;
    if (i >= total) return;
    int e = i / 75, d4 = i - e * 75;
    int r = ei[e];
    int c = ei[E + e];
    int a0 = ea[e * 3 + 0], a1 = ea[e * 3 + 1], a2 = ea[e * 3 + 2];
    const float4* b4 = (const float4*)bemb;
    float4 ev0 = b4[(size_t)a0 * 75 + d4];
    float4 ev1 = b4[(size_t)(8 + a1) * 75 + d4];
    float4 ev2 = b4[(size_t)(16 + a2) * 75 + d4];
    float4 hv = ((const float4*)h)[(size_t)r * 75 + d4];
    float m0 = hv.x + ev0.x + ev1.x + ev2.x;
    float m1 = hv.y + ev0.y + ev1.y + ev2.y;
    float m2 = hv.z + ev0.z + ev1.z + ev2.z;
    float m3 = hv.w + ev0.w + ev1.w + ev2.w;
    float* dst = agg + (size_t)c * EMBD + d4 * 4;
    if (m0 > 0.f) atomicAdd(dst + 0, m0);
    if (m1 > 0.f) atomicAdd(dst + 1, m1);
    if (m2 > 0.f) atomicAdd(dst + 2, m2);
    if (m3 > 0.f) atomicAdd(dst + 3, m3);
}

// one block per graph: pooled[g][t] = sum over nodes of h[n][t]
__global__ void pool_graphs(const float* __restrict__ h, const int* __restrict__ starts,
                            float* __restrict__ pooled) {
    int g = blockIdx.x;
    int t = threadIdx.x;
    if (t >= EMBD) return;
    int s0 = starts[g], s1 = starts[g + 1];
    float s = 0.f;
    for (int n = s0; n < s1; ++n) s += h[(size_t)n * EMBD + t];
    pooled[(size_t)g * EMBD + t] = s;
}

// final: out[g][t] = mean over nodes
__global__ void pool_mean(const float* __restrict__ h, const int* __restrict__ starts,
                          float* __restrict__ out) {
    int g = blockIdx.x;
    int t = threadIdx.x;
    if (t >= EMBD) return;
    int s0 = starts[g], s1 = starts[g + 1];
    float s = 0.f;
    for (int n = s0; n < s1; ++n) s += h[(size_t)n * EMBD + t];
    float cnt = (float)(s1 - s0);
    out[(size_t)g * EMBD + t] = s / fmaxf(cnt, 1.0f);
}

// ---------------- split / transpose kernels ----------------

// in [M][Kreal] fp32 (+optional add2, same shape) -> H,L ushort [M][KP], zero-padded
__global__ void conv_split(const float* __restrict__ in, const float* __restrict__ add2,
                           ushort_t* __restrict__ H, ushort_t* __restrict__ L,
                           int M, int Kreal, int KP) {
    int i = blockIdx.x * blockDim.x + threadIdx.x;
    int total = M * KP;
    if (i >= total) return;
    int r = i / KP, k = i - r * KP;
    float v = 0.f;
    if (k < Kreal) {
        v = in[(size_t)r * Kreal + k];
        if (add2) v += add2[(size_t)r * Kreal + k];
    }
    ushort_t hh, ll;
    bf16_split(v, hh, ll);
    H[i] = hh;
    L[i] = ll;
}

// W [K][Nn] fp32 -> HT,LT ushort [NnP][KP] (transposed, zero-padded)
__global__ void conv_wT(const float* __restrict__ W, ushort_t* __restrict__ HT,
                        ushort_t* __restrict__ LT, int K, int Nn, int KP, int NnP) {
    int i = blockIdx.x * blockDim.x + threadIdx.x;
    int total = NnP * KP;
    if (i >= total) return;
    int n = i / KP, k = i - n * KP;
    float v = (n < Nn && k < K) ? W[(size_t)k * Nn + n] : 0.f;
    ushort_t hh, ll;
    bf16_split(v, hh, ll);
    HT[i] = hh;
    LT[i] = ll;
}

// ---------------- split-bf16 MFMA GEMM ----------------
// C = epilogue( (Ah+Al) @ (Bh+Bl)^T ), B stored transposed [NnP][KP]
// epilogue: y = (acc + bias - bm)*(g*rsqrt(bv+eps)) + bb ; optional relu
// out mode A: fp32 [Mc][ldF] (cols < NnReal only)
// out mode B: bf16 pair ushort [Mc][ldP] (all padded cols written; pads are zero)
#define BMg 256
#define BNg 64

__global__ __launch_bounds__(256) void gemm_split(
    const ushort_t* __restrict__ AH, const ushort_t* __restrict__ AL, int KP,
    const ushort_t* __restrict__ BH, const ushort_t* __restrict__ BL,
    const float* __restrict__ bias, const float* __restrict__ gg,
    const float* __restrict__ bb, const float* __restrict__ bm,
    const float* __restrict__ bv,
    int Mc, int NnReal, int relu,
    float* __restrict__ outF, int ldF,
    ushort_t* __restrict__ outH, ushort_t* __restrict__ outL, int ldP)
{
    __shared__ ushort_t sAH[BMg * 32];   // 16 KB, swizzled quad layout
    __shared__ ushort_t sAL[BMg * 32];
    __shared__ ushort_t sBH[BNg * 32];   // 4 KB
    __shared__ ushort_t sBL[BNg * 32];

    const int tid = threadIdx.x;
    const int lane = tid & 63;
    const int w = tid >> 6;
    const int m0 = blockIdx.y * BMg;
    const int n0 = blockIdx.x * BNg;

    // ---- precompute DMA pointers; advance 64B (32 ushorts) per k-tile ----
    // slot s holds global (m, q) at LDS offset s*16B where s = m*4 + q',
    // q' = (q + (m>>1)) & 3   (2-way-max bank aliasing on fragment reads)
    const ushort_t* gA[8];
    ushort_t* lA[8];
    const ushort_t* gB[2];
    ushort_t* lB[2];
#pragma unroll
    for (int i = 0; i < 4; ++i) {
        int s = w * 256 + i * 64 + lane;
        int m = s >> 2, qp = s & 3;
        int q = (qp - (m >> 1)) & 3;
        int msrc = (m0 + m < Mc) ? (m0 + m) : (Mc - 1);
        gA[i]     = AH + (size_t)msrc * KP + 8 * q;
        gA[i + 4] = AL + (size_t)msrc * KP + 8 * q;
        lA[i]     = sAH + (w * 256 + i * 64) * 8;   // wave-uniform base
        lA[i + 4] = sAL + (w * 256 + i * 64) * 8;
    }
    {
        int s = w * 64 + lane;
        int n = s >> 2, qp = s & 3;
        int q = (qp - (n >> 1)) & 3;
        gB[0] = BH + (size_t)(n0 + n) * KP + 8 * q;
        gB[1] = BL + (size_t)(n0 + n) * KP + 8 * q;
        lB[0] = sBH + (w * 64) * 8;
        lB[1] = sBL + (w * 64) * 8;
    }

    f32x4 acc[4][4];
#pragma unroll
    for (int a = 0; a < 4; ++a)
#pragma unroll
        for (int b = 0; b < 4; ++b) acc[a][b] = (f32x4)(0.f);

    const int q = lane >> 4;
    const int c16 = lane & 15;
    const int kt = KP >> 5;

    for (int t = 0; t < kt; ++t) {
        if (t) __syncthreads();
#pragma unroll
        for (int i = 0; i < 8; ++i) { dma16(gA[i], lA[i]); gA[i] += 32; }
        dma16(gB[0], lB[0]); gB[0] += 32;
        dma16(gB[1], lB[1]); gB[1] += 32;
        __syncthreads();   // drains vmcnt before barrier release

        short8 ah[4], al[4], bh[4], bl[4];
#pragma unroll
        for (int tt = 0; tt < 4; ++tt) {
            int m = w * 64 + tt * 16 + c16;
            int q2 = (q + (m >> 1)) & 3;
            int off = m * 32 + q2 * 8;
            ah[tt] = *(const short8*)(sAH + off);
            al[tt] = *(const short8*)(sAL + off);
        }
#pragma unroll
        for (int uu = 0; uu < 4; ++uu) {
            int n = uu * 16 + c16;
            int q2 = (q + (n >> 1)) & 3;
            int off = n * 32 + q2 * 8;
            bh[uu] = *(const short8*)(sBH + off);
            bl[uu] = *(const short8*)(sBL + off);
        }
#pragma unroll
        for (int tt = 0; tt < 4; ++tt)
#pragma unroll
            for (int uu = 0; uu < 4; ++uu) {
                acc[tt][uu] = __builtin_amdgcn_mfma_f32_16x16x32_bf16(ah[tt], bh[uu], acc[tt][uu], 0, 0, 0);
                acc[tt][uu] = __builtin_amdgcn_mfma_f32_16x16x32_bf16(ah[tt], bl[uu], acc[tt][uu], 0, 0, 0);
                acc[tt][uu] = __builtin_amdgcn_mfma_f32_16x16x32_bf16(al[tt], bh[uu], acc[tt][uu], 0, 0, 0);
            }
    }

    // ---- epilogue: C/D layout col=lane&15, row=(lane>>4)*4+r ----
#pragma unroll
    for (int uu = 0; uu < 4; ++uu) {
        int gn = n0 + uu * 16 + c16;
        float sc = 0.f, sh = 0.f;
        if (gn < NnReal) {
            sc = gg[gn] * rsqrtf(bv[gn] + 1e-5f);
            sh = bb[gn] + (bias[gn] - bm[gn]) * sc;
        }
#pragma unroll
        for (int tt = 0; tt < 4; ++tt) {
            int rbase = m0 + w * 64 + tt * 16 + q * 4;
#pragma unroll
            for (int r = 0; r < 4; ++r) {
                int gm = rbase + r;
                if (gm >= Mc) continue;
                float y = acc[tt][uu][r] * sc + sh;
                if (relu) y = fmaxf(y, 0.f);
                if (outF) {
                    if (gn < NnReal) outF[(size_t)gm * ldF + gn] = y;
                } else {
                    ushort_t hh, ll;
                    bf16_split(y, hh, ll);
                    outH[(size_t)gm * ldP + gn] = hh;
                    outL[(size_t)gm * ldP + gn] = ll;
                }
            }
        }
    }
}

// ---------------- host-side chunked MLP ----------------

struct MlpW {
    const float *W1, *b1, *g1, *be1, *m1, *v1;
    const float *W2, *b2, *g2, *be2, *m2, *v2;
};

// in: [M][300] fp32 (+add2) -> out fp32 [M][300] at outF (relu2 optional)
static void run_mlp(hipStream_t stream, const float* in, const float* add2, int M,
                    ushort_t* w1h, ushort_t* w1l, ushort_t* w2h, ushort_t* w2l,
                    ushort_t* aH, ushort_t* aL, ushort_t* tH, ushort_t* tL, int CH,
                    const MlpW& W, float* outF, int relu2) {
    const int BLK = 256;
    // weight conversion
    conv_wT<<<cdiv(NP1 * KP1, BLK), BLK, 0, stream>>>(W.W1, w1h, w1l, EMBD, 2 * EMBD, KP1, NP1);
    conv_wT<<<cdiv(NP2 * KP2, BLK), BLK, 0, stream>>>(W.W2, w2h, w2l, 2 * EMBD, EMBD, KP2, NP2);
    for (int c0 = 0; c0 < M; c0 += CH) {
        int Mc = (M - c0 < CH) ? (M - c0) : CH;
        conv_split<<<cdiv(Mc * KP1, BLK), BLK, 0, stream>>>(
            in + (size_t)c0 * EMBD, add2 ? add2 + (size_t)c0 * EMBD : nullptr,
            aH, aL, Mc, EMBD, KP1);
        {
            dim3 grid(NP1 / BNg, cdiv(Mc, BMg));
            gemm_split<<<grid, 256, 0, stream>>>(
                aH, aL, KP1, w1h, w1l,
                W.b1, W.g1, W.be1, W.m1, W.v1,
                Mc, 2 * EMBD, 1,
                nullptr, 0, tH, tL, KP2);
        }
        {
            dim3 grid(NP2 / BNg, cdiv(Mc, BMg));
            gemm_split<<<grid, 256, 0, stream>>>(
                tH, tL, KP2, w2h, w2l,
                W.b2, W.g2, W.be2, W.m2, W.v2,
                Mc, EMBD, relu2,
                outF + (size_t)c0 * EMBD, EMBD, nullptr, nullptr, 0);
        }
    }
}

// ---------------- entry ----------------

extern "C" void kernel_launch(void* const* d_in, const int* in_sizes, int n_in,
                              void* d_out, int out_size, void* d_ws, size_t ws_size,
                              hipStream_t stream) {
    const int*   x        = (const int*)d_in[0];
    const int*   ei       = (const int*)d_in[1];
    const int*   ea       = (const int*)d_in[2];
    const int*   batch    = (const int*)d_in[3];
    const float* atom_emb = (const float*)d_in[4];
    const float* bond_emb = (const float*)d_in[5];
    const float* vn_emb   = (const float*)d_in[6];
    const float* gin_eps  = (const float*)d_in[7];
    const float* gin_W1   = (const float*)d_in[8];
    const float* gin_b1   = (const float*)d_in[9];
    const float* gin_bn1g = (const float*)d_in[10];
    const float* gin_bn1b = (const float*)d_in[11];
    const float* gin_bn1m = (const float*)d_in[12];
    const float* gin_bn1v = (const float*)d_in[13];
    const float* gin_W2   = (const float*)d_in[14];
    const float* gin_b2   = (const float*)d_in[15];
    const float* bn_g     = (const float*)d_in[16];
    const float* bn_b     = (const float*)d_in[17];
    const float* bn_m     = (const float*)d_in[18];
    const float* bn_v     = (const float*)d_in[19];
    const float* vn_W1    = (const float*)d_in[20];
    const float* vn_b1    = (const float*)d_in[21];
    const float* vn_bn1g  = (const float*)d_in[22];
    const float* vn_bn1b  = (const float*)d_in[23];
    const float* vn_bn1m  = (const float*)d_in[24];
    const float* vn_bn1v  = (const float*)d_in[25];
    const float* vn_W2    = (const float*)d_in[26];
    const float* vn_b2    = (const float*)d_in[27];
    const float* vn_bn2g  = (const float*)d_in[28];
    const float* vn_bn2b  = (const float*)d_in[29];
    const float* vn_bn2m  = (const float*)d_in[30];
    const float* vn_bn2v  = (const float*)d_in[31];

    const int N = in_sizes[3];
    const int E = in_sizes[1] / 2;

    // ---- workspace layout (bytes), fixed part ~251.5 MB ----
    char* base = (char*)d_ws;
    size_t off = 0;
    float* hbuf   = (float*)(base + off); off += (size_t)N * EMBD * 4;
    float* agg    = (float*)(base + off); off += (size_t)N * EMBD * 4;
    float* vnbuf  = (float*)(base + off); off += (size_t)GG * EMBD * 4;
    float* pooled = (float*)(base + off); off += (size_t)GG * EMBD * 4;
    int*   starts = (int*)(base + off);   off += 4104 * 4;
    ushort_t* w1h = (ushort_t*)(base + off); off += (size_t)NP1 * KP1 * 2;
    ushort_t* w1l = (ushort_t*)(base + off); off += (size_t)NP1 * KP1 * 2;
    ushort_t* w2h = (ushort_t*)(base + off); off += (size_t)NP2 * KP2 * 2;
    ushort_t* w2l = (ushort_t*)(base + off); off += (size_t)NP2 * KP2 * 2;

    // adaptive chunk area: per-row 3840 B (aggH/L 320*2*2 + t2H/L 640*2*2)
    size_t avail = (ws_size > off) ? ws_size - off : 0;
    int CH = (int)(avail / 3840);
    CH &= ~63;                 // 16B-align every sub-buffer
    if (CH > N) CH = (N + 63) & ~63;
    if (CH < 256) CH = 256;    // last resort
    ushort_t* aH = (ushort_t*)(base + off);
    ushort_t* aL = aH + (size_t)CH * KP1;
    ushort_t* tH = aL + (size_t)CH * KP1;
    ushort_t* tL = tH + (size_t)CH * KP2;

    const int BLK = 256;
    int ne4 = N * 75;
    int ee4 = E * 75;

    find_starts<<<cdiv(GG + 1, BLK), BLK, 0, stream>>>(batch, starts, N);
    atom_encode4<<<cdiv(ne4, BLK), BLK, 0, stream>>>(x, atom_emb, hbuf, N);
    init_vn4<<<cdiv(GG * 75, BLK), BLK, 0, stream>>>(vn_emb, vnbuf);

    for (int l = 0; l < NLAY; ++l) {
        int last = (l == NLAY - 1);

        prep4<<<cdiv(ne4, BLK), BLK, 0, stream>>>(hbuf, agg, vnbuf, batch, gin_eps + l, N);
        edge_scatter4<<<cdiv(ee4, BLK), BLK, 0, stream>>>(hbuf, ei, ea, bond_emb, agg, E);
        if (!last)
            pool_graphs<<<GG, 320, 0, stream>>>(hbuf, starts, pooled);

        // node MLP: hbuf = bn(mlp(agg)) (+relu unless last)
        MlpW Wn = { gin_W1 + (size_t)l * EMBD * 2 * EMBD, gin_b1 + (size_t)l * 2 * EMBD,
                    gin_bn1g + (size_t)l * 2 * EMBD, gin_bn1b + (size_t)l * 2 * EMBD,
                    gin_bn1m + (size_t)l * 2 * EMBD, gin_bn1v + (size_t)l * 2 * EMBD,
                    gin_W2 + (size_t)l * 2 * EMBD * EMBD, gin_b2 + (size_t)l * EMBD,
                    bn_g + (size_t)l * EMBD, bn_b + (size_t)l * EMBD,
                    bn_m + (size_t)l * EMBD, bn_v + (size_t)l * EMBD };
        run_mlp(stream, agg, nullptr, N, w1h, w1l, w2h, w2l, aH, aL, tH, tL, CH,
                Wn, hbuf, last ? 0 : 1);

        if (!last) {
            // virtual-node MLP: vnbuf = relu(bn2(mlp(pooled + vnbuf)))
            MlpW Wv = { vn_W1 + (size_t)l * EMBD * 2 * EMBD, vn_b1 + (size_t)l * 2 * EMBD,
                        vn_bn1g + (size_t)l * 2 * EMBD, vn_bn1b + (size_t)l * 2 * EMBD,
                        vn_bn1m + (size_t)l * 2 * EMBD, vn_bn1v + (size_t)l * 2 * EMBD,
                        vn_W2 + (size_t)l * 2 * EMBD * EMBD, vn_b2 + (size_t)l * EMBD,
                        vn_bn2g + (size_t)l * EMBD, vn_bn2b + (size_t)l * EMBD,
                        vn_bn2m + (size_t)l * EMBD, vn_bn2v + (size_t)l * EMBD };
            run_mlp(stream, pooled, vnbuf, GG, w1h, w1l, w2h, w2l, aH, aL, tH, tL, CH,
                    Wv, vnbuf, 1);
        }
    }

    pool_mean<<<GG, 320, 0, stream>>>(hbuf, starts, (float*)d_out);
}